// Round 6
// baseline (76.824 us; speedup 1.0000x reference)
//
#include <hip/hip_runtime.h>
#include <hip/hip_bf16.h>

typedef __attribute__((ext_vector_type(8))) short bfrag;   // 8 bf16
typedef __attribute__((ext_vector_type(4))) float f32x4;

typedef __attribute__((address_space(1))) const void GV;
typedef __attribute__((address_space(3))) void LV;

// ================= fused prep: norms+xb | wt | pe2 (all float4) =========
__global__ void k_prep(const float* __restrict__ x,
                       const float* __restrict__ w,
                       const float* __restrict__ tcb,
                       float* __restrict__ norms,
                       __hip_bfloat16* __restrict__ xb,
                       __hip_bfloat16* __restrict__ wt,
                       float* __restrict__ pe2) {
    int blk = blockIdx.x;
    if (blk < 2048) {
        int i = blk * 256 + threadIdx.x;            // 524288 quads
        f32x4 v = *(const f32x4*)&x[i * 4];
        __hip_bfloat16 h[4];
        h[0] = __float2bfloat16(v.x);
        h[1] = __float2bfloat16(v.y);
        h[2] = __float2bfloat16(v.z);
        h[3] = __float2bfloat16(v.w);
        *(short4*)&xb[i * 4] = *(const short4*)h;
        float a = fabsf(v.x) + fabsf(v.y) + fabsf(v.z) + fabsf(v.w);
        a += __shfl_xor(a, 1);
        a += __shfl_xor(a, 2);
        a += __shfl_xor(a, 4);
        a += __shfl_xor(a, 8);                      // 16-lane row reduce
        if ((threadIdx.x & 15) == 0) norms[i >> 4] = a;
    } else if (blk < 2432) {
        int i = (blk - 2048) * 256 + threadIdx.x;   // 98304
        int d = i / 192, kk = i - d * 192;
        int c = kk & 63, k = kk >> 6;
        wt[i] = __float2bfloat16(w[d * 192 + c * 3 + k]);
    } else {
        int j = (blk - 2432) * 256 + threadIdx.x;   // 262144 d-quads
        int s = j >> 7, q = j & 127;
        f32x4 tb = *(const f32x4*)&tcb[q * 4];
        float dv0 = expf((float)(4 * q)     * (-9.210340371976184f / 512.0f));
        float dv1 = expf((float)(4 * q + 2) * (-9.210340371976184f / 512.0f));
        float s0v, c0v, s1v, c1v;
        sincosf((float)s * dv0, &s0v, &c0v);
        sincosf((float)s * dv1, &s1v, &c1v);
        f32x4 r = {s0v + tb.x, c0v + tb.y, s1v + tb.z, c1v + tb.w};
        *(f32x4*)&pe2[s * 512 + q * 4] = r;
    }
}

// ====== conv-GEMM + inline tc scan; 1024 blocks, 2 d-passes each ======
// Block = (b, s-tile) x d-half. Bs = circular 130-row xb window (staged
// once, T2-swizzled both sides). tc for the 128 s-values computed by the
// block's own waves (ballot backward scan over norms) into LDS while the
// staging loads are in flight. XCD x owns s-tiles {2x,2x+1}.
__launch_bounds__(256, 4)
__global__ void k_gemm(const __hip_bfloat16* __restrict__ xb,
                       const __hip_bfloat16* __restrict__ wt,
                       const float* __restrict__ pe2,
                       const float* __restrict__ norms,
                       const float* __restrict__ tcw,
                       float* __restrict__ out) {
    __shared__ alignas(16) __hip_bfloat16 Bs[130 * 64];    // 16.25 KB
    __shared__ float tcs[128];

    const int bid = blockIdx.x;
    const int xcd = bid & 7, u = bid >> 3;          // u in [0,128)
    const int st = (xcd << 1) | (u & 1);
    const int bb = (u >> 1) & 15;
    const int d0base = (u >> 5) << 6;               // {0,64,128,192}
    const int s0 = st << 7;
    const int tid = threadIdx.x;
    const int lane = tid & 63;
    const int wv = tid >> 6;
    const int wd = wv >> 1, ws = wv & 1;            // wave tile: 32(d) x 64(s)
    const int lhi = lane >> 4, ll = lane & 15;

    // ---- stage B (xb): 130 rows x 8 16B-chunks, circular, pre-swizzled ----
#pragma unroll
    for (int i = 0; i < 5; ++i) {
        int q = tid + i * 256;
        if (q < 1040) {
            int row = q >> 3, uu = q & 7;
            int us = uu ^ (row & 7);
            int sg = (s0 - 1 + row) & 2047;
            const __hip_bfloat16* src =
                xb + (size_t)((bb << 11) + sg) * 64 + us * 8;
            __builtin_amdgcn_global_load_lds((GV*)src, (LV*)(Bs + q * 8), 16, 0, 0);
        }
    }

    // ---- tc scan for this block's 128 s-values (overlaps staging) ----
    {
        const float* nb = norms + (bb << 11);
        for (int j = 0; j < 32; ++j) {
            int tl = wv * 32 + j;
            int t = s0 + tl;
            float thresh = 0.7f * (nb[t] + 1e-8f);
            int res = 0;
            for (int Wd = (t - 1) >> 8; Wd >= 0; --Wd) {
                int sBase = Wd * 256 + 4 * lane;
                f32x4 v = *(const f32x4*)&nb[sBase];
                int best = -1;
                if (sBase + 0 < t && v.x < thresh) best = sBase + 0;
                if (sBase + 1 < t && v.y < thresh) best = sBase + 1;
                if (sBase + 2 < t && v.z < thresh) best = sBase + 2;
                if (sBase + 3 < t && v.w < thresh) best = sBase + 3;
                unsigned long long m = __ballot(best >= 0);
                if (m) {
                    int L = 63 - __clzll(m);        // highest lane = largest s
                    res = t - __shfl(best, L);
                    break;
                }
            }
            if (lane == 0) tcs[tl] = (float)res;
        }
    }
    __syncthreads();

    for (int dp = 0; dp < 2; ++dp) {
        const int d0 = d0base + dp * 256;
        const __hip_bfloat16* wbase =
            wt + (size_t)(d0 + wd * 32 + ll) * 192 + lhi * 8;
        bfrag af[2][2];
#pragma unroll
        for (int kc = 0; kc < 2; ++kc)
#pragma unroll
            for (int m = 0; m < 2; ++m)
                af[kc][m] = *(const bfrag*)(wbase + m * 16 * 192 + kc * 32);

        f32x4 acc[2][4] = {};
#pragma unroll
        for (int k = 0; k < 3; ++k) {
            bfrag an[2][2];
            if (k < 2) {                            // prefetch tap k+1
#pragma unroll
                for (int kc = 0; kc < 2; ++kc)
#pragma unroll
                    for (int m = 0; m < 2; ++m)
                        an[kc][m] = *(const bfrag*)(wbase + m * 16 * 192 +
                                                    (k + 1) * 64 + kc * 32);
            }
#pragma unroll
            for (int kc = 0; kc < 2; ++kc) {
                bfrag bf[4];
                const int colB = kc * 64 + lhi * 16;
#pragma unroll
                for (int n = 0; n < 4; ++n) {
                    int rl = ws * 64 + n * 16 + ll + k;
                    bf[n] = *(const bfrag*)((const char*)Bs + rl * 128 +
                                            (colB ^ ((rl & 7) << 4)));
                }
#pragma unroll
                for (int m = 0; m < 2; ++m)
#pragma unroll
                    for (int n = 0; n < 4; ++n)
                        acc[m][n] = __builtin_amdgcn_mfma_f32_16x16x32_bf16(
                            af[kc][m], bf[n], acc[m][n], 0, 0, 0);
            }
#pragma unroll
            for (int kc = 0; kc < 2; ++kc)
#pragma unroll
                for (int m = 0; m < 2; ++m)
                    af[kc][m] = an[kc][m];
        }

        // ---- epilogue: float4 everywhere, tc from LDS ----
        f32x4 tw[2];
#pragma unroll
        for (int m = 0; m < 2; ++m)
            tw[m] = *(const f32x4*)&tcw[d0 + wd * 32 + m * 16 + lhi * 4];
#pragma unroll
        for (int n = 0; n < 4; ++n) {
            const int sl = ws * 64 + n * 16 + ll;
            const int sCol = s0 + sl;
            const float tcv = tcs[sl];
            const size_t orow = ((size_t)(bb << 11) + sCol) * 512;
#pragma unroll
            for (int m = 0; m < 2; ++m) {
                const int dbase = d0 + wd * 32 + m * 16 + lhi * 4;
                f32x4 pw = *(const f32x4*)&pe2[sCol * 512 + dbase];
                f32x4 r = acc[m][n] + pw + tcv * tw[m];
                *(f32x4*)&out[orow + dbase] = r;
            }
        }
    }
}

extern "C" void kernel_launch(void* const* d_in, const int* in_sizes, int n_in,
                              void* d_out, int out_size, void* d_ws, size_t ws_size,
                              hipStream_t stream) {
    const float* x   = (const float*)d_in[0];   // (16,2048,64)
    const float* cw  = (const float*)d_in[1];   // (512,64,3)
    const float* tcw = (const float*)d_in[2];   // (512,1)
    const float* tcb = (const float*)d_in[3];   // (512,)
    float* out = (float*)d_out;

    char* ws = (char*)d_ws;
    __hip_bfloat16* xb  = (__hip_bfloat16*)(ws);             // 4,194,304 B
    __hip_bfloat16* wt  = (__hip_bfloat16*)(ws + 4194304);   //   196,608 B
    float* pe2          = (float*)(ws + 4390912);            // 4,194,304 B
    float* norms        = (float*)(ws + 8585216);            //   131,072 B

    hipLaunchKernelGGL(k_prep, dim3(3456), dim3(256), 0, stream,
                       x, cw, tcb, norms, xb, wt, pe2);
    hipLaunchKernelGGL(k_gemm, dim3(1024), dim3(256), 0, stream,
                       xb, wt, pe2, norms, tcw, out);
}

// Round 7
// 66.949 us; speedup vs baseline: 1.1475x; 1.1475x over previous
//
#include <hip/hip_runtime.h>
#include <hip/hip_bf16.h>

typedef __attribute__((ext_vector_type(8))) short bfrag;   // 8 bf16
typedef __attribute__((ext_vector_type(4))) float f32x4;

typedef __attribute__((address_space(1))) const void GV;
typedef __attribute__((address_space(3))) void LV;

// ================= fused prep: norms+xb | wt | pe2 (all float4) =========
__global__ void k_prep(const float* __restrict__ x,
                       const float* __restrict__ w,
                       const float* __restrict__ tcb,
                       float* __restrict__ norms,
                       __hip_bfloat16* __restrict__ xb,
                       __hip_bfloat16* __restrict__ wt,
                       float* __restrict__ pe2) {
    int blk = blockIdx.x;
    if (blk < 2048) {
        int i = blk * 256 + threadIdx.x;            // 524288 quads
        f32x4 v = *(const f32x4*)&x[i * 4];
        __hip_bfloat16 h[4];
        h[0] = __float2bfloat16(v.x);
        h[1] = __float2bfloat16(v.y);
        h[2] = __float2bfloat16(v.z);
        h[3] = __float2bfloat16(v.w);
        *(short4*)&xb[i * 4] = *(const short4*)h;
        float a = fabsf(v.x) + fabsf(v.y) + fabsf(v.z) + fabsf(v.w);
        a += __shfl_xor(a, 1);
        a += __shfl_xor(a, 2);
        a += __shfl_xor(a, 4);
        a += __shfl_xor(a, 8);                      // 16-lane row reduce
        if ((threadIdx.x & 15) == 0) norms[i >> 4] = a;
    } else if (blk < 2432) {
        int i = (blk - 2048) * 256 + threadIdx.x;   // 98304
        int d = i / 192, kk = i - d * 192;
        int c = kk & 63, k = kk >> 6;
        wt[i] = __float2bfloat16(w[d * 192 + c * 3 + k]);
    } else {
        int j = (blk - 2432) * 256 + threadIdx.x;   // 262144 d-quads
        int s = j >> 7, q = j & 127;
        f32x4 tb = *(const f32x4*)&tcb[q * 4];
        float dv0 = expf((float)(4 * q)     * (-9.210340371976184f / 512.0f));
        float dv1 = expf((float)(4 * q + 2) * (-9.210340371976184f / 512.0f));
        float s0v, c0v, s1v, c1v;
        sincosf((float)s * dv0, &s0v, &c0v);
        sincosf((float)s * dv1, &s1v, &c1v);
        f32x4 r = {s0v + tb.x, c0v + tb.y, s1v + tb.z, c1v + tb.w};
        *(f32x4*)&pe2[s * 512 + q * 4] = r;
    }
}

// ---------- tc[b][t]: wave-per-t, 256-wide aligned float4 windows ----------
__global__ void k_tc(const float* __restrict__ norms, float* __restrict__ tc) {
    int gid = blockIdx.x * 256 + threadIdx.x;
    int wave = gid >> 6;                  // 32768 = (b,t)
    int lane = threadIdx.x & 63;
    int b = wave >> 11, t = wave & 2047;
    const float* nb = norms + (b << 11);
    float thresh = 0.7f * (nb[t] + 1e-8f);
    int res = 0;
    for (int W = (t - 1) >> 8; W >= 0; --W) {       // t=0 -> W=-1, skipped
        int sBase = W * 256 + 4 * lane;
        f32x4 v = *(const f32x4*)&nb[sBase];        // 16B aligned
        int best = -1;
        if (sBase + 0 < t && v.x < thresh) best = sBase + 0;
        if (sBase + 1 < t && v.y < thresh) best = sBase + 1;
        if (sBase + 2 < t && v.z < thresh) best = sBase + 2;
        if (sBase + 3 < t && v.w < thresh) best = sBase + 3;
        unsigned long long m = __ballot(best >= 0);
        if (m) {                                    // highest lane = largest s
            int L = 63 - __clzll(m);
            int smax = __shfl(best, L);
            res = t - smax;
            break;
        }
    }
    if (lane == 0) tc[wave] = (float)res;
}

// =========== conv-GEMM: A (wt) direct from L2, B (xb) in LDS ===========
// 2048 blocks, 8/CU. 64(d) x 128(s) tile, K=192. Nontemporal out stores.
// XCD x owns s-tiles {2x,2x+1} -> pe2/xb slices stay L2-resident.
__launch_bounds__(256, 8)
__global__ void k_gemm(const __hip_bfloat16* __restrict__ xb,
                       const __hip_bfloat16* __restrict__ wt,
                       const float* __restrict__ pe2,
                       const float* __restrict__ tc,
                       const float* __restrict__ tcw,
                       float* __restrict__ out) {
    __shared__ alignas(16) __hip_bfloat16 Bs[130 * 64];    // 16.25 KB

    const int bid = blockIdx.x;
    const int xcd = bid & 7, u = bid >> 3;       // u in [0,256)
    const int st = (xcd << 1) | (u & 1);
    const int bb = (u >> 1) & 15;
    const int d0 = (u >> 5) << 6;                // {0,64,...,448}
    const int s0 = st << 7;
    const int tid = threadIdx.x;
    const int lane = tid & 63;
    const int wv = tid >> 6;
    const int wd = wv >> 1, ws = wv & 1;         // wave tile: 32(d) x 64(s)
    const int lhi = lane >> 4, ll = lane & 15;

    // ---- stage B (xb): 130 rows x 8 16B-chunks, circular, pre-swizzled ----
#pragma unroll
    for (int i = 0; i < 5; ++i) {
        int q = tid + i * 256;
        if (q < 1040) {
            int row = q >> 3, uu = q & 7;
            int us = uu ^ (row & 7);
            int sg = (s0 - 1 + row) & 2047;
            const __hip_bfloat16* src =
                xb + (size_t)((bb << 11) + sg) * 64 + us * 8;
            __builtin_amdgcn_global_load_lds((GV*)src, (LV*)(Bs + q * 8), 16, 0, 0);
        }
    }

    // ---- A fragments for tap 0 straight from global (wt is L2-hot) ----
    const __hip_bfloat16* wbase =
        wt + (size_t)(d0 + wd * 32 + ll) * 192 + lhi * 8;
    bfrag af[2][2];                               // [kc][m]
#pragma unroll
    for (int kc = 0; kc < 2; ++kc)
#pragma unroll
        for (int m = 0; m < 2; ++m)
            af[kc][m] = *(const bfrag*)(wbase + m * 16 * 192 + kc * 32);

    __syncthreads();

    f32x4 acc[2][4] = {};
#pragma unroll
    for (int k = 0; k < 3; ++k) {
        bfrag an[2][2];
        if (k < 2) {                              // prefetch tap k+1
#pragma unroll
            for (int kc = 0; kc < 2; ++kc)
#pragma unroll
                for (int m = 0; m < 2; ++m)
                    an[kc][m] = *(const bfrag*)(wbase + m * 16 * 192 +
                                                (k + 1) * 64 + kc * 32);
        }
#pragma unroll
        for (int kc = 0; kc < 2; ++kc) {
            bfrag bf[4];
            const int colB = kc * 64 + lhi * 16;
#pragma unroll
            for (int n = 0; n < 4; ++n) {
                int rl = ws * 64 + n * 16 + ll + k;
                bf[n] = *(const bfrag*)((const char*)Bs + rl * 128 +
                                        (colB ^ ((rl & 7) << 4)));
            }
#pragma unroll
            for (int m = 0; m < 2; ++m)
#pragma unroll
                for (int n = 0; n < 4; ++n)
                    acc[m][n] = __builtin_amdgcn_mfma_f32_16x16x32_bf16(
                        af[kc][m], bf[n], acc[m][n], 0, 0, 0);
        }
#pragma unroll
        for (int kc = 0; kc < 2; ++kc)
#pragma unroll
            for (int m = 0; m < 2; ++m)
                af[kc][m] = an[kc][m];
    }

    // ---- epilogue: float4 loads, nontemporal float4 stores ----
    f32x4 tw[2];
#pragma unroll
    for (int m = 0; m < 2; ++m)
        tw[m] = *(const f32x4*)&tcw[d0 + wd * 32 + m * 16 + lhi * 4];
#pragma unroll
    for (int n = 0; n < 4; ++n) {
        const int sCol = s0 + ws * 64 + n * 16 + ll;
        const float tcv = tc[(bb << 11) + sCol];
        const size_t orow = ((size_t)(bb << 11) + sCol) * 512;
#pragma unroll
        for (int m = 0; m < 2; ++m) {
            const int dbase = d0 + wd * 32 + m * 16 + lhi * 4;
            f32x4 pw = *(const f32x4*)&pe2[sCol * 512 + dbase];
            f32x4 r = acc[m][n] + pw + tcv * tw[m];
            __builtin_nontemporal_store(r, (f32x4*)&out[orow + dbase]);
        }
    }
}

extern "C" void kernel_launch(void* const* d_in, const int* in_sizes, int n_in,
                              void* d_out, int out_size, void* d_ws, size_t ws_size,
                              hipStream_t stream) {
    const float* x   = (const float*)d_in[0];   // (16,2048,64)
    const float* cw  = (const float*)d_in[1];   // (512,64,3)
    const float* tcw = (const float*)d_in[2];   // (512,1)
    const float* tcb = (const float*)d_in[3];   // (512,)
    float* out = (float*)d_out;

    char* ws = (char*)d_ws;
    __hip_bfloat16* xb  = (__hip_bfloat16*)(ws);             // 4,194,304 B
    __hip_bfloat16* wt  = (__hip_bfloat16*)(ws + 4194304);   //   196,608 B
    float* pe2          = (float*)(ws + 4390912);            // 4,194,304 B
    float* norms        = (float*)(ws + 8585216);            //   131,072 B
    float* tc           = (float*)(ws + 8716288);            //   131,072 B

    hipLaunchKernelGGL(k_prep, dim3(3456), dim3(256), 0, stream,
                       x, cw, tcb, norms, xb, wt, pe2);
    hipLaunchKernelGGL(k_tc,   dim3(8192), dim3(256), 0, stream, norms, tc);
    hipLaunchKernelGGL(k_gemm, dim3(2048), dim3(256), 0, stream,
                       xb, wt, pe2, tc, tcw, out);
}

// Round 8
// 49.798 us; speedup vs baseline: 1.5427x; 1.3444x over previous
//
#include <hip/hip_runtime.h>
#include <hip/hip_bf16.h>

typedef __attribute__((ext_vector_type(8))) short bfrag;   // 8 bf16
typedef __attribute__((ext_vector_type(4))) float f32x4;

typedef __attribute__((address_space(1))) const void GV;
typedef __attribute__((address_space(3))) void LV;

// ================= fused prep: norms+xb | wt | pe2 (all float4) =========
__global__ void k_prep(const float* __restrict__ x,
                       const float* __restrict__ w,
                       const float* __restrict__ tcb,
                       float* __restrict__ norms,
                       __hip_bfloat16* __restrict__ xb,
                       __hip_bfloat16* __restrict__ wt,
                       float* __restrict__ pe2) {
    int blk = blockIdx.x;
    if (blk < 2048) {
        int i = blk * 256 + threadIdx.x;            // 524288 quads
        f32x4 v = *(const f32x4*)&x[i * 4];
        __hip_bfloat16 h[4];
        h[0] = __float2bfloat16(v.x);
        h[1] = __float2bfloat16(v.y);
        h[2] = __float2bfloat16(v.z);
        h[3] = __float2bfloat16(v.w);
        *(short4*)&xb[i * 4] = *(const short4*)h;
        float a = fabsf(v.x) + fabsf(v.y) + fabsf(v.z) + fabsf(v.w);
        a += __shfl_xor(a, 1);
        a += __shfl_xor(a, 2);
        a += __shfl_xor(a, 4);
        a += __shfl_xor(a, 8);                      // 16-lane row reduce
        if ((threadIdx.x & 15) == 0) norms[i >> 4] = a;
    } else if (blk < 2432) {
        int i = (blk - 2048) * 256 + threadIdx.x;   // 98304
        int d = i / 192, kk = i - d * 192;
        int c = kk & 63, k = kk >> 6;
        wt[i] = __float2bfloat16(w[d * 192 + c * 3 + k]);
    } else {
        int j = (blk - 2432) * 256 + threadIdx.x;   // 262144 d-quads
        int s = j >> 7, q = j & 127;
        f32x4 tb = *(const f32x4*)&tcb[q * 4];
        float dv0 = expf((float)(4 * q)     * (-9.210340371976184f / 512.0f));
        float dv1 = expf((float)(4 * q + 2) * (-9.210340371976184f / 512.0f));
        float s0v, c0v, s1v, c1v;
        sincosf((float)s * dv0, &s0v, &c0v);
        sincosf((float)s * dv1, &s1v, &c1v);
        f32x4 r = {s0v + tb.x, c0v + tb.y, s1v + tb.z, c1v + tb.w};
        *(f32x4*)&pe2[s * 512 + q * 4] = r;
    }
}

// ---------- tc[b][t]: wave-per-t, 256-wide aligned float4 windows ----------
__global__ void k_tc(const float* __restrict__ norms, float* __restrict__ tc) {
    int gid = blockIdx.x * 256 + threadIdx.x;
    int wave = gid >> 6;                  // 32768 = (b,t)
    int lane = threadIdx.x & 63;
    int b = wave >> 11, t = wave & 2047;
    const float* nb = norms + (b << 11);
    float thresh = 0.7f * (nb[t] + 1e-8f);
    int res = 0;
    for (int W = (t - 1) >> 8; W >= 0; --W) {       // t=0 -> W=-1, skipped
        int sBase = W * 256 + 4 * lane;
        f32x4 v = *(const f32x4*)&nb[sBase];        // 16B aligned
        int best = -1;
        if (sBase + 0 < t && v.x < thresh) best = sBase + 0;
        if (sBase + 1 < t && v.y < thresh) best = sBase + 1;
        if (sBase + 2 < t && v.z < thresh) best = sBase + 2;
        if (sBase + 3 < t && v.w < thresh) best = sBase + 3;
        unsigned long long m = __ballot(best >= 0);
        if (m) {                                    // highest lane = largest s
            int L = 63 - __clzll(m);
            int smax = __shfl(best, L);
            res = t - smax;
            break;
        }
    }
    if (lane == 0) tc[wave] = (float)res;
}

// =========== conv-GEMM: A (wt) direct from L2, B (xb) in LDS ===========
// 2048 blocks, 6/CU. 64(d) x 128(s) tile, K=192. Cached float4 stores
// (L2 merges each wave's 256B/row bursts into full lines — nt stores
// caused 2.8x write amplification in R7).
__launch_bounds__(256, 6)
__global__ void k_gemm(const __hip_bfloat16* __restrict__ xb,
                       const __hip_bfloat16* __restrict__ wt,
                       const float* __restrict__ pe2,
                       const float* __restrict__ tc,
                       const float* __restrict__ tcw,
                       float* __restrict__ out) {
    __shared__ alignas(16) __hip_bfloat16 Bs[130 * 64];    // 16.25 KB

    const int bid = blockIdx.x;
    const int xcd = bid & 7, u = bid >> 3;       // u in [0,256)
    const int st = (xcd << 1) | (u & 1);
    const int bb = (u >> 1) & 15;
    const int d0 = (u >> 5) << 6;                // {0,64,...,448}
    const int s0 = st << 7;
    const int tid = threadIdx.x;
    const int lane = tid & 63;
    const int wv = tid >> 6;
    const int wd = wv >> 1, ws = wv & 1;         // wave tile: 32(d) x 64(s)
    const int lhi = lane >> 4, ll = lane & 15;

    // ---- stage B (xb): 130 rows x 8 16B-chunks, circular, pre-swizzled ----
#pragma unroll
    for (int i = 0; i < 5; ++i) {
        int q = tid + i * 256;
        if (q < 1040) {
            int row = q >> 3, uu = q & 7;
            int us = uu ^ (row & 7);
            int sg = (s0 - 1 + row) & 2047;
            const __hip_bfloat16* src =
                xb + (size_t)((bb << 11) + sg) * 64 + us * 8;
            __builtin_amdgcn_global_load_lds((GV*)src, (LV*)(Bs + q * 8), 16, 0, 0);
        }
    }

    // ---- A fragments for tap 0 straight from global (wt is L2-hot) ----
    const __hip_bfloat16* wbase =
        wt + (size_t)(d0 + wd * 32 + ll) * 192 + lhi * 8;
    bfrag af[2][2];                               // [kc][m]
#pragma unroll
    for (int kc = 0; kc < 2; ++kc)
#pragma unroll
        for (int m = 0; m < 2; ++m)
            af[kc][m] = *(const bfrag*)(wbase + m * 16 * 192 + kc * 32);

    __syncthreads();

    f32x4 acc[2][4] = {};
#pragma unroll
    for (int k = 0; k < 3; ++k) {
        bfrag an[2][2];
        if (k < 2) {                              // prefetch tap k+1
#pragma unroll
            for (int kc = 0; kc < 2; ++kc)
#pragma unroll
                for (int m = 0; m < 2; ++m)
                    an[kc][m] = *(const bfrag*)(wbase + m * 16 * 192 +
                                                (k + 1) * 64 + kc * 32);
        }
#pragma unroll
        for (int kc = 0; kc < 2; ++kc) {
            bfrag bf[4];
            const int colB = kc * 64 + lhi * 16;
#pragma unroll
            for (int n = 0; n < 4; ++n) {
                int rl = ws * 64 + n * 16 + ll + k;
                bf[n] = *(const bfrag*)((const char*)Bs + rl * 128 +
                                        (colB ^ ((rl & 7) << 4)));
            }
#pragma unroll
            for (int m = 0; m < 2; ++m)
#pragma unroll
                for (int n = 0; n < 4; ++n)
                    acc[m][n] = __builtin_amdgcn_mfma_f32_16x16x32_bf16(
                        af[kc][m], bf[n], acc[m][n], 0, 0, 0);
        }
#pragma unroll
        for (int kc = 0; kc < 2; ++kc)
#pragma unroll
            for (int m = 0; m < 2; ++m)
                af[kc][m] = an[kc][m];
    }

    // ---- epilogue: float4 loads, cached float4 stores ----
    f32x4 tw[2];
#pragma unroll
    for (int m = 0; m < 2; ++m)
        tw[m] = *(const f32x4*)&tcw[d0 + wd * 32 + m * 16 + lhi * 4];
#pragma unroll
    for (int n = 0; n < 4; ++n) {
        const int sCol = s0 + ws * 64 + n * 16 + ll;
        const float tcv = tc[(bb << 11) + sCol];
        const size_t orow = ((size_t)(bb << 11) + sCol) * 512;
#pragma unroll
        for (int m = 0; m < 2; ++m) {
            const int dbase = d0 + wd * 32 + m * 16 + lhi * 4;
            f32x4 pw = *(const f32x4*)&pe2[sCol * 512 + dbase];
            f32x4 r = acc[m][n] + pw + tcv * tw[m];
            *(f32x4*)&out[orow + dbase] = r;
        }
    }
}

extern "C" void kernel_launch(void* const* d_in, const int* in_sizes, int n_in,
                              void* d_out, int out_size, void* d_ws, size_t ws_size,
                              hipStream_t stream) {
    const float* x   = (const float*)d_in[0];   // (16,2048,64)
    const float* cw  = (const float*)d_in[1];   // (512,64,3)
    const float* tcw = (const float*)d_in[2];   // (512,1)
    const float* tcb = (const float*)d_in[3];   // (512,)
    float* out = (float*)d_out;

    char* ws = (char*)d_ws;
    __hip_bfloat16* xb  = (__hip_bfloat16*)(ws);             // 4,194,304 B
    __hip_bfloat16* wt  = (__hip_bfloat16*)(ws + 4194304);   //   196,608 B
    float* pe2          = (float*)(ws + 4390912);            // 4,194,304 B
    float* norms        = (float*)(ws + 8585216);            //   131,072 B
    float* tc           = (float*)(ws + 8716288);            //   131,072 B

    hipLaunchKernelGGL(k_prep, dim3(3456), dim3(256), 0, stream,
                       x, cw, tcb, norms, xb, wt, pe2);
    hipLaunchKernelGGL(k_tc,   dim3(8192), dim3(256), 0, stream, norms, tc);
    hipLaunchKernelGGL(k_gemm, dim3(2048), dim3(256), 0, stream,
                       xb, wt, pe2, tc, tcw, out);
}

// Round 9
// 42.913 us; speedup vs baseline: 1.7902x; 1.1605x over previous
//
#include <hip/hip_runtime.h>
#include <hip/hip_bf16.h>

typedef __attribute__((ext_vector_type(8))) short bfrag;   // 8 bf16
typedef __attribute__((ext_vector_type(4))) float f32x4;

typedef __attribute__((address_space(1))) const void GV;
typedef __attribute__((address_space(3))) void LV;

static __device__ __forceinline__ float b2f(short s) {
    unsigned u = ((unsigned)(unsigned short)s) << 16;
    float f;
    __builtin_memcpy(&f, &u, 4);
    return f;
}

// ============ fused prep: norms+xb | wt | pe2b(bf16) — all vector ============
__global__ void k_prep(const float* __restrict__ x,
                       const float* __restrict__ w,
                       const float* __restrict__ tcb,
                       float* __restrict__ norms,
                       __hip_bfloat16* __restrict__ xb,
                       __hip_bfloat16* __restrict__ wt,
                       __hip_bfloat16* __restrict__ pe2b) {
    int blk = blockIdx.x;
    if (blk < 2048) {
        int i = blk * 256 + threadIdx.x;            // 524288 quads
        f32x4 v = *(const f32x4*)&x[i * 4];
        __hip_bfloat16 h[4];
        h[0] = __float2bfloat16(v.x);
        h[1] = __float2bfloat16(v.y);
        h[2] = __float2bfloat16(v.z);
        h[3] = __float2bfloat16(v.w);
        *(short4*)&xb[i * 4] = *(const short4*)h;
        float a = fabsf(v.x) + fabsf(v.y) + fabsf(v.z) + fabsf(v.w);
        a += __shfl_xor(a, 1);
        a += __shfl_xor(a, 2);
        a += __shfl_xor(a, 4);
        a += __shfl_xor(a, 8);                      // 16-lane row reduce
        if ((threadIdx.x & 15) == 0) norms[i >> 4] = a;
    } else if (blk < 2432) {
        int i = (blk - 2048) * 256 + threadIdx.x;   // 98304
        int d = i / 192, kk = i - d * 192;
        int c = kk & 63, k = kk >> 6;
        wt[i] = __float2bfloat16(w[d * 192 + c * 3 + k]);
    } else {
        int j = (blk - 2432) * 256 + threadIdx.x;   // 262144 d-quads
        int s = j >> 7, q = j & 127;
        f32x4 tb = *(const f32x4*)&tcb[q * 4];
        float dv0 = expf((float)(4 * q)     * (-9.210340371976184f / 512.0f));
        float dv1 = expf((float)(4 * q + 2) * (-9.210340371976184f / 512.0f));
        float s0v, c0v, s1v, c1v;
        sincosf((float)s * dv0, &s0v, &c0v);
        sincosf((float)s * dv1, &s1v, &c1v);
        __hip_bfloat16 h[4];
        h[0] = __float2bfloat16(s0v + tb.x);
        h[1] = __float2bfloat16(c0v + tb.y);
        h[2] = __float2bfloat16(s1v + tb.z);
        h[3] = __float2bfloat16(c1v + tb.w);
        *(short4*)&pe2b[s * 512 + q * 4] = *(const short4*)h;
    }
}

// ---------- tc[b][t]: wave-per-t, 256-wide aligned float4 windows ----------
__global__ void k_tc(const float* __restrict__ norms, float* __restrict__ tc) {
    int gid = blockIdx.x * 256 + threadIdx.x;
    int wave = gid >> 6;                  // 32768 = (b,t)
    int lane = threadIdx.x & 63;
    int b = wave >> 11, t = wave & 2047;
    const float* nb = norms + (b << 11);
    float thresh = 0.7f * (nb[t] + 1e-8f);
    int res = 0;
    for (int W = (t - 1) >> 8; W >= 0; --W) {
        int sBase = W * 256 + 4 * lane;
        f32x4 v = *(const f32x4*)&nb[sBase];
        int best = -1;
        if (sBase + 0 < t && v.x < thresh) best = sBase + 0;
        if (sBase + 1 < t && v.y < thresh) best = sBase + 1;
        if (sBase + 2 < t && v.z < thresh) best = sBase + 2;
        if (sBase + 3 < t && v.w < thresh) best = sBase + 3;
        unsigned long long m = __ballot(best >= 0);
        if (m) {                                    // highest lane = largest s
            int L = 63 - __clzll(m);
            int smax = __shfl(best, L);
            res = t - smax;
            break;
        }
    }
    if (lane == 0) tc[wave] = (float)res;
}

// ========= conv-GEMM: 1024 blocks, 128(d) x 128(s), wave = 32d x 128s =========
// VMEM-issue-lean: Bs(xb) + Ps(pe bf16) + Ts(tc) staged via global_load_lds,
// wt fragments direct from L2 (zero intra-block redundancy), float4 stores.
__launch_bounds__(256, 3)
__global__ void k_gemm(const __hip_bfloat16* __restrict__ xb,
                       const __hip_bfloat16* __restrict__ wt,
                       const __hip_bfloat16* __restrict__ pe2b,
                       const float* __restrict__ tc,
                       const float* __restrict__ tcw,
                       float* __restrict__ out) {
    __shared__ alignas(16) __hip_bfloat16 Bs[130 * 64];     // 16.64 KB
    __shared__ alignas(16) __hip_bfloat16 Ps[128 * 128];    // 32 KB
    __shared__ alignas(16) float Ts[128];                   // 0.5 KB

    const int bid = blockIdx.x;
    const int xcd = bid & 7, u = bid >> 3;       // u in [0,128)
    const int st = (xcd << 1) | (u & 1);
    const int bb = (u >> 1) & 15;
    const int d0 = (u >> 5) << 7;                // {0,128,256,384}
    const int s0 = st << 7;
    const int tid = threadIdx.x;
    const int lane = tid & 63;
    const int wd = tid >> 6;                     // wave owns 32 d-rows
    const int lhi = lane >> 4, ll = lane & 15;

    // ---- stage B (xb): 130 rows x 8 chunks, circular, pre-swizzled src ----
#pragma unroll
    for (int i = 0; i < 5; ++i) {
        int q = tid + i * 256;
        if (q < 1040) {
            int row = q >> 3, uu = q & 7;
            int us = uu ^ (row & 7);
            int sg = (s0 - 1 + row) & 2047;
            const __hip_bfloat16* src =
                xb + (size_t)((bb << 11) + sg) * 64 + us * 8;
            __builtin_amdgcn_global_load_lds((GV*)src, (LV*)(Bs + q * 8), 16, 0, 0);
        }
    }
    // ---- stage P (pe2b): 128 rows x 16 chunks, chunk-XOR swizzled src ----
#pragma unroll
    for (int i = 0; i < 8; ++i) {
        int q = tid + i * 256;                   // 2048 chunks
        int sl = q >> 4, c = q & 15;
        int cs = c ^ (sl & 7);
        const __hip_bfloat16* src = pe2b + (size_t)(s0 + sl) * 512 + d0 + cs * 8;
        __builtin_amdgcn_global_load_lds((GV*)src, (LV*)(Ps + q * 8), 16, 0, 0);
    }
    // ---- stage T (tc slice): 128 floats = 32 chunks ----
    if (tid < 32) {
        const float* src = tc + (bb << 11) + s0 + tid * 4;
        __builtin_amdgcn_global_load_lds((GV*)src, (LV*)(Ts + tid * 4), 16, 0, 0);
    }

    // ---- A fragments tap 0 direct from global (wt L2-hot, no redundancy) ----
    const __hip_bfloat16* wbase =
        wt + (size_t)(d0 + wd * 32 + ll) * 192 + lhi * 8;
    bfrag af[2][2];                               // [kc][m]
#pragma unroll
    for (int kc = 0; kc < 2; ++kc)
#pragma unroll
        for (int m = 0; m < 2; ++m)
            af[kc][m] = *(const bfrag*)(wbase + m * 16 * 192 + kc * 32);

    __syncthreads();

    f32x4 acc[2][8] = {};
#pragma unroll
    for (int k = 0; k < 3; ++k) {
        bfrag an[2][2];
        if (k < 2) {                              // prefetch tap k+1
#pragma unroll
            for (int kc = 0; kc < 2; ++kc)
#pragma unroll
                for (int m = 0; m < 2; ++m)
                    an[kc][m] = *(const bfrag*)(wbase + m * 16 * 192 +
                                                (k + 1) * 64 + kc * 32);
        }
#pragma unroll
        for (int kc = 0; kc < 2; ++kc) {
            const int colB = kc * 64 + lhi * 16;
            bfrag bf[8];
#pragma unroll
            for (int n = 0; n < 8; ++n) {
                int rl = n * 16 + ll + k;         // 0..129
                bf[n] = *(const bfrag*)((const char*)Bs + rl * 128 +
                                        (colB ^ ((rl & 7) << 4)));
            }
#pragma unroll
            for (int m = 0; m < 2; ++m)
#pragma unroll
                for (int n = 0; n < 8; ++n)
                    acc[m][n] = __builtin_amdgcn_mfma_f32_16x16x32_bf16(
                        af[kc][m], bf[n], acc[m][n], 0, 0, 0);
        }
#pragma unroll
        for (int kc = 0; kc < 2; ++kc)
#pragma unroll
            for (int m = 0; m < 2; ++m)
                af[kc][m] = an[kc][m];
    }

    // ---- epilogue: pe/tc from LDS, float4 stores ----
    f32x4 tw[2];
#pragma unroll
    for (int m = 0; m < 2; ++m)
        tw[m] = *(const f32x4*)&tcw[d0 + wd * 32 + m * 16 + lhi * 4];
#pragma unroll
    for (int n = 0; n < 8; ++n) {
        const int sl = n * 16 + ll;
        const int sCol = s0 + sl;
        const float tcv = Ts[sl];
        const size_t orow = ((size_t)(bb << 11) + sCol) * 512;
#pragma unroll
        for (int m = 0; m < 2; ++m) {
            const int dloc = wd * 32 + m * 16 + lhi * 4;
            const int pbyte = sl * 256 + ((((dloc >> 3) ^ (sl & 7)) << 4) |
                                          ((dloc << 1) & 15));
            const short4 pv = *(const short4*)((const char*)Ps + pbyte);
            f32x4 r = acc[m][n];
            r.x += b2f(pv.x) + tcv * tw[m].x;
            r.y += b2f(pv.y) + tcv * tw[m].y;
            r.z += b2f(pv.z) + tcv * tw[m].z;
            r.w += b2f(pv.w) + tcv * tw[m].w;
            *(f32x4*)&out[orow + d0 + dloc] = r;
        }
    }
}

extern "C" void kernel_launch(void* const* d_in, const int* in_sizes, int n_in,
                              void* d_out, int out_size, void* d_ws, size_t ws_size,
                              hipStream_t stream) {
    const float* x   = (const float*)d_in[0];   // (16,2048,64)
    const float* cw  = (const float*)d_in[1];   // (512,64,3)
    const float* tcw = (const float*)d_in[2];   // (512,1)
    const float* tcb = (const float*)d_in[3];   // (512,)
    float* out = (float*)d_out;

    char* ws = (char*)d_ws;
    __hip_bfloat16* xb   = (__hip_bfloat16*)(ws);            // 4,194,304 B
    __hip_bfloat16* wt   = (__hip_bfloat16*)(ws + 4194304);  //   196,608 B
    __hip_bfloat16* pe2b = (__hip_bfloat16*)(ws + 4390912);  // 2,097,152 B
    float* norms         = (float*)(ws + 6488064);           //   131,072 B
    float* tc            = (float*)(ws + 6619136);           //   131,072 B

    hipLaunchKernelGGL(k_prep, dim3(3456), dim3(256), 0, stream,
                       x, cw, tcb, norms, xb, wt, pe2b);
    hipLaunchKernelGGL(k_tc,   dim3(8192), dim3(256), 0, stream, norms, tc);
    hipLaunchKernelGGL(k_gemm, dim3(1024), dim3(256), 0, stream,
                       xb, wt, pe2b, tc, tcw, out);
}

// Round 10
// 40.248 us; speedup vs baseline: 1.9088x; 1.0662x over previous
//
#include <hip/hip_runtime.h>
#include <hip/hip_bf16.h>

typedef __attribute__((ext_vector_type(8))) short bfrag;   // 8 bf16
typedef __attribute__((ext_vector_type(4))) float f32x4;

typedef __attribute__((address_space(1))) const void GV;
typedef __attribute__((address_space(3))) void LV;

static __device__ __forceinline__ float b2f(short s) {
    unsigned u = ((unsigned)(unsigned short)s) << 16;
    float f;
    __builtin_memcpy(&f, &u, 4);
    return f;
}

// ============ fused prep: norms+xb | wt | pe2b(bf16) — all vector ============
__global__ void k_prep(const float* __restrict__ x,
                       const float* __restrict__ w,
                       const float* __restrict__ tcb,
                       float* __restrict__ norms,
                       __hip_bfloat16* __restrict__ xb,
                       __hip_bfloat16* __restrict__ wt,
                       __hip_bfloat16* __restrict__ pe2b) {
    int blk = blockIdx.x;
    if (blk < 2048) {
        int i = blk * 256 + threadIdx.x;            // 524288 quads
        f32x4 v = *(const f32x4*)&x[i * 4];
        __hip_bfloat16 h[4];
        h[0] = __float2bfloat16(v.x);
        h[1] = __float2bfloat16(v.y);
        h[2] = __float2bfloat16(v.z);
        h[3] = __float2bfloat16(v.w);
        *(short4*)&xb[i * 4] = *(const short4*)h;
        float a = fabsf(v.x) + fabsf(v.y) + fabsf(v.z) + fabsf(v.w);
        a += __shfl_xor(a, 1);
        a += __shfl_xor(a, 2);
        a += __shfl_xor(a, 4);
        a += __shfl_xor(a, 8);                      // 16-lane row reduce
        if ((threadIdx.x & 15) == 0) norms[i >> 4] = a;
    } else if (blk < 2432) {
        int i = (blk - 2048) * 256 + threadIdx.x;   // 98304
        int d = i / 192, kk = i - d * 192;
        int c = kk & 63, k = kk >> 6;
        wt[i] = __float2bfloat16(w[d * 192 + c * 3 + k]);
    } else {
        int j = (blk - 2432) * 256 + threadIdx.x;   // 262144 d-quads
        int s = j >> 7, q = j & 127;
        f32x4 tb = *(const f32x4*)&tcb[q * 4];
        float dv0 = expf((float)(4 * q)     * (-9.210340371976184f / 512.0f));
        float dv1 = expf((float)(4 * q + 2) * (-9.210340371976184f / 512.0f));
        float s0v, c0v, s1v, c1v;
        sincosf((float)s * dv0, &s0v, &c0v);
        sincosf((float)s * dv1, &s1v, &c1v);
        __hip_bfloat16 h[4];
        h[0] = __float2bfloat16(s0v + tb.x);
        h[1] = __float2bfloat16(c0v + tb.y);
        h[2] = __float2bfloat16(s1v + tb.z);
        h[3] = __float2bfloat16(c1v + tb.w);
        *(short4*)&pe2b[s * 512 + q * 4] = *(const short4*)h;
    }
}

// ---------- tc[b][t]: wave-per-t, 256-wide aligned float4 windows ----------
__global__ void k_tc(const float* __restrict__ norms, float* __restrict__ tc) {
    int gid = blockIdx.x * 256 + threadIdx.x;
    int wave = gid >> 6;                  // 32768 = (b,t)
    int lane = threadIdx.x & 63;
    int b = wave >> 11, t = wave & 2047;
    const float* nb = norms + (b << 11);
    float thresh = 0.7f * (nb[t] + 1e-8f);
    int res = 0;
    for (int W = (t - 1) >> 8; W >= 0; --W) {
        int sBase = W * 256 + 4 * lane;
        f32x4 v = *(const f32x4*)&nb[sBase];
        int best = -1;
        if (sBase + 0 < t && v.x < thresh) best = sBase + 0;
        if (sBase + 1 < t && v.y < thresh) best = sBase + 1;
        if (sBase + 2 < t && v.z < thresh) best = sBase + 2;
        if (sBase + 3 < t && v.w < thresh) best = sBase + 3;
        unsigned long long m = __ballot(best >= 0);
        if (m) {                                    // highest lane = largest s
            int L = 63 - __clzll(m);
            int smax = __shfl(best, L);
            res = t - smax;
            break;
        }
    }
    if (lane == 0) tc[wave] = (float)res;
}

// ========= conv-GEMM: 1024 blocks, 128(d) x 128(s), wave = 32d x 128s =========
// Phase split: {Bs stage + all wt frags} -> bar1 -> {issue Ps/Ts stage, MFMA
// (pure LDS+MFMA, Ps lands underneath)} -> bar2 -> epilogue from LDS.
__launch_bounds__(256, 3)
__global__ void k_gemm(const __hip_bfloat16* __restrict__ xb,
                       const __hip_bfloat16* __restrict__ wt,
                       const __hip_bfloat16* __restrict__ pe2b,
                       const float* __restrict__ tc,
                       const float* __restrict__ tcw,
                       float* __restrict__ out) {
    __shared__ alignas(16) __hip_bfloat16 Bs[130 * 64];     // 16.64 KB
    __shared__ alignas(16) __hip_bfloat16 Ps[128 * 128];    // 32 KB
    __shared__ alignas(16) float Ts[128];                   // 0.5 KB

    const int bid = blockIdx.x;
    const int xcd = bid & 7, u = bid >> 3;       // u in [0,128)
    const int st = (xcd << 1) | (u & 1);
    const int bb = (u >> 1) & 15;
    const int d0 = (u >> 5) << 7;                // {0,128,256,384}
    const int s0 = st << 7;
    const int tid = threadIdx.x;
    const int lane = tid & 63;
    const int wd = tid >> 6;                     // wave owns 32 d-rows
    const int lhi = lane >> 4, ll = lane & 15;

    // ---- stage B (xb): 130 rows x 8 chunks, circular, pre-swizzled src ----
#pragma unroll
    for (int i = 0; i < 5; ++i) {
        int q = tid + i * 256;
        if (q < 1040) {
            int row = q >> 3, uu = q & 7;
            int us = uu ^ (row & 7);
            int sg = (s0 - 1 + row) & 2047;
            const __hip_bfloat16* src =
                xb + (size_t)((bb << 11) + sg) * 64 + us * 8;
            __builtin_amdgcn_global_load_lds((GV*)src, (LV*)(Bs + q * 8), 16, 0, 0);
        }
    }

    // ---- ALL wt fragments (3 taps) direct from L2, issued pre-barrier ----
    const __hip_bfloat16* wbase =
        wt + (size_t)(d0 + wd * 32 + ll) * 192 + lhi * 8;
    bfrag af[3][2][2];                            // [tap][kc][m]
#pragma unroll
    for (int k = 0; k < 3; ++k)
#pragma unroll
        for (int kc = 0; kc < 2; ++kc)
#pragma unroll
            for (int m = 0; m < 2; ++m)
                af[k][kc][m] = *(const bfrag*)(wbase + m * 16 * 192 +
                                               k * 64 + kc * 32);

    __syncthreads();   // drains Bs (Ps not yet issued)

    // ---- issue P (pe2b) + T (tc) staging: lands during the MFMA phase ----
#pragma unroll
    for (int i = 0; i < 8; ++i) {
        int q = tid + i * 256;                   // 2048 chunks
        int sl = q >> 4, c = q & 15;
        int cs = c ^ (sl & 7);
        const __hip_bfloat16* src = pe2b + (size_t)(s0 + sl) * 512 + d0 + cs * 8;
        __builtin_amdgcn_global_load_lds((GV*)src, (LV*)(Ps + q * 8), 16, 0, 0);
    }
    if (tid < 32) {
        const float* src = tc + (bb << 11) + s0 + tid * 4;
        __builtin_amdgcn_global_load_lds((GV*)src, (LV*)(Ts + tid * 4), 16, 0, 0);
    }
    f32x4 tw[2];
#pragma unroll
    for (int m = 0; m < 2; ++m)
        tw[m] = *(const f32x4*)&tcw[d0 + wd * 32 + m * 16 + lhi * 4];

    // ---- MFMA phase: pure ds_read + mfma ----
    f32x4 acc[2][8] = {};
#pragma unroll
    for (int k = 0; k < 3; ++k) {
#pragma unroll
        for (int kc = 0; kc < 2; ++kc) {
            const int colB = kc * 64 + lhi * 16;
            bfrag bf[8];
#pragma unroll
            for (int n = 0; n < 8; ++n) {
                int rl = n * 16 + ll + k;         // 0..129
                bf[n] = *(const bfrag*)((const char*)Bs + rl * 128 +
                                        (colB ^ ((rl & 7) << 4)));
            }
#pragma unroll
            for (int m = 0; m < 2; ++m)
#pragma unroll
                for (int n = 0; n < 8; ++n)
                    acc[m][n] = __builtin_amdgcn_mfma_f32_16x16x32_bf16(
                        af[k][kc][m], bf[n], acc[m][n], 0, 0, 0);
        }
    }

    __syncthreads();   // drains Ps/Ts

    // ---- epilogue: pe/tc from LDS, float4 stores ----
#pragma unroll
    for (int n = 0; n < 8; ++n) {
        const int sl = n * 16 + ll;
        const int sCol = s0 + sl;
        const float tcv = Ts[sl];
        const size_t orow = ((size_t)(bb << 11) + sCol) * 512;
#pragma unroll
        for (int m = 0; m < 2; ++m) {
            const int dloc = wd * 32 + m * 16 + lhi * 4;
            const int pbyte = sl * 256 + ((((dloc >> 3) ^ (sl & 7)) << 4) |
                                          ((dloc << 1) & 15));
            const short4 pv = *(const short4*)((const char*)Ps + pbyte);
            f32x4 r = acc[m][n];
            r.x += b2f(pv.x) + tcv * tw[m].x;
            r.y += b2f(pv.y) + tcv * tw[m].y;
            r.z += b2f(pv.z) + tcv * tw[m].z;
            r.w += b2f(pv.w) + tcv * tw[m].w;
            *(f32x4*)&out[orow + d0 + dloc] = r;
        }
    }
}

extern "C" void kernel_launch(void* const* d_in, const int* in_sizes, int n_in,
                              void* d_out, int out_size, void* d_ws, size_t ws_size,
                              hipStream_t stream) {
    const float* x   = (const float*)d_in[0];   // (16,2048,64)
    const float* cw  = (const float*)d_in[1];   // (512,64,3)
    const float* tcw = (const float*)d_in[2];   // (512,1)
    const float* tcb = (const float*)d_in[3];   // (512,)
    float* out = (float*)d_out;

    char* ws = (char*)d_ws;
    __hip_bfloat16* xb   = (__hip_bfloat16*)(ws);            // 4,194,304 B
    __hip_bfloat16* wt   = (__hip_bfloat16*)(ws + 4194304);  //   196,608 B
    __hip_bfloat16* pe2b = (__hip_bfloat16*)(ws + 4390912);  // 2,097,152 B
    float* norms         = (float*)(ws + 6488064);           //   131,072 B
    float* tc            = (float*)(ws + 6619136);           //   131,072 B

    hipLaunchKernelGGL(k_prep, dim3(3456), dim3(256), 0, stream,
                       x, cw, tcb, norms, xb, wt, pe2b);
    hipLaunchKernelGGL(k_tc,   dim3(8192), dim3(256), 0, stream, norms, tc);
    hipLaunchKernelGGL(k_gemm, dim3(1024), dim3(256), 0, stream,
                       xb, wt, pe2b, tc, tcw, out);
}